// Round 12
// baseline (2633.483 us; speedup 1.0000x reference)
//
#include <hip/hip_runtime.h>
#include <hip/hip_fp16.h>

typedef _Float16 half8 __attribute__((ext_vector_type(8)));
typedef _Float16 half4v __attribute__((ext_vector_type(4)));
typedef float f32x4 __attribute__((ext_vector_type(4)));

#define T_INS 200

// LDS layout (bytes) — weights now fully register-resident; only h/x tiles.
constexpr int H0O  = 0;      // 2 x 4096 (parity)
constexpr int H1O  = 8192;   // 2 x 4096
constexpr int XTO  = 16384;  // 2 x 4096
constexpr int SMSZ = 24576;  // 24 KiB

constexpr size_t WSZ_PACK = 524288;  // 4 x 128KB frag regions

// swizzled [batch][k(half)] f16 layout (2-way max bank aliasing on b128)
#define OFF(b, k) (((((b) << 8) | ((k) << 1))) ^ (((b) & 7) << 4))

// counted barrier: publish LDS only; global loads/stores stay in flight
#define BARRIER() asm volatile("s_waitcnt lgkmcnt(0)\n\ts_barrier" ::: "memory")

__device__ __forceinline__ float sigm(float x) {
  return __builtin_amdgcn_rcpf(1.0f + __builtin_amdgcn_exp2f(-1.44269504f * x));
}
__device__ __forceinline__ float tanh_f(float x) {
  return 1.0f - 2.0f * __builtin_amdgcn_rcpf(1.0f + __builtin_amdgcn_exp2f(2.88539008f * x));
}
__device__ __forceinline__ half8 cvt_frag(const float* __restrict__ src) {
  f32x4 a = *(const f32x4*)src;
  f32x4 b = *(const f32x4*)(src + 4);
  half8 h;
  h[0] = (_Float16)a[0]; h[1] = (_Float16)a[1]; h[2] = (_Float16)a[2]; h[3] = (_Float16)a[3];
  h[4] = (_Float16)b[0]; h[5] = (_Float16)b[1]; h[6] = (_Float16)b[2]; h[7] = (_Float16)b[3];
  return h;
}
__device__ __forceinline__ half8 cvt_frag_s(const float* __restrict__ src, float s) {
  f32x4 a = *(const f32x4*)src;
  f32x4 b = *(const f32x4*)(src + 4);
  half8 h;
  h[0] = (_Float16)(s * a[0]); h[1] = (_Float16)(s * a[1]);
  h[2] = (_Float16)(s * a[2]); h[3] = (_Float16)(s * a[3]);
  h[4] = (_Float16)(s * b[0]); h[5] = (_Float16)(s * b[1]);
  h[6] = (_Float16)(s * b[2]); h[7] = (_Float16)(s * b[3]);
  return h;
}
// 8-wave row permutation: gate = r&3, unit = w*16 + (r>>2)*4 + mt
__device__ __forceinline__ int perm_row8(int w, int mt, int r) {
  return (r & 3) * 128 + w * 16 + (r >> 2) * 4 + mt;
}

// gates with pre-scaled z (SCALED: i,f,o rows x -log2e; g rows x 2*log2e)
template <int SCALED>
__device__ __forceinline__ float gates(const f32x4 a, float& c, bool mk) {
  float si, sf, tg, so;
  if (SCALED) {
    si = __builtin_amdgcn_rcpf(1.0f + __builtin_amdgcn_exp2f(a[0]));
    sf = __builtin_amdgcn_rcpf(1.0f + __builtin_amdgcn_exp2f(a[1]));
    tg = 1.0f - 2.0f * __builtin_amdgcn_rcpf(1.0f + __builtin_amdgcn_exp2f(a[2]));
    so = __builtin_amdgcn_rcpf(1.0f + __builtin_amdgcn_exp2f(a[3]));
  } else {
    si = sigm(a[0]); sf = sigm(a[1]); tg = tanh_f(a[2]); so = sigm(a[3]);
  }
  float cn = sf * c + si * tg;
  float hn = so * tanh_f(cn);
  c = mk ? cn : c;
  return hn;
}

// Pack into ws (PRE-SCALED rows): region 0 = W_ih[1], 1 = W_hh[0],
// 2 = W_hh[1], 3 = W_ih[0]. Frag F = w*16 + mt*4 + kf; 64 lanes x 16B.
__global__ __launch_bounds__(256) void pack_kernel(const float* __restrict__ W_ih,
                                                   const float* __restrict__ W_hh,
                                                   char* __restrict__ ws) {
  int gid = blockIdx.x * 256 + threadIdx.x;  // 32768 threads exactly
  int G = gid >> 6, lane = gid & 63;
  int region = G >> 7, F = G & 127;
  int w = F >> 4, mt = (F >> 2) & 3, kf = F & 3;
  int r = lane & 15;
  int row = perm_row8(w, mt, r);
  int k0 = kf * 32 + (lane >> 4) * 8;
  float s = ((r & 3) == 2) ? 2.88539008f : -1.44269504f;
  const float* src;
  if (region == 0)      src = W_ih + (size_t)(512 + row) * 128 + k0;
  else if (region == 3) src = W_ih + (size_t)row * 128 + k0;
  else                  src = W_hh + (size_t)((region - 1) * 512 + row) * 128 + k0;
  *(half8*)(ws + (size_t)G * 1024 + lane * 16) = cvt_frag_s(src, s);
}

#define READ_BF(BF, BASE)                                                     \
  _Pragma("unroll") for (int kf = 0; kf < 4; ++kf)                            \
      BF[kf] = *(const half8*)((BASE) + OFF(lb, kf * 32 + k0b));

template <int PACKED>
__global__ __launch_bounds__(512, 2) void lstm_kernel(
    const float* __restrict__ x, const int* __restrict__ len_in,
    const int* __restrict__ len_ar, const float* __restrict__ W_ih,
    const float* __restrict__ W_hh, const float* __restrict__ b_ih,
    const float* __restrict__ b_hh, const char* __restrict__ ws,
    float* __restrict__ out) {
  __shared__ __attribute__((aligned(16))) char sm[SMSZ];

  const int tid = threadIdx.x;
  const int w = tid >> 6, lane = tid & 63;
  const int lb = lane & 15, lg = lane >> 4;
  const int k0b = lg * 8;
  const int u0 = w * 16 + lg * 4;  // lane's 4 contiguous units: u0..u0+3
  const int batch = blockIdx.x * 16 + lb;
  const int Lin = len_in[batch];
  const int Lar = len_ar[batch];

  // ---- one-time init ----
  // zero h0/h1 (both parities): 16 KiB
#pragma unroll
  for (int i = 0; i < 2; ++i)
    *(f32x4*)(sm + H0O + tid * 16 + i * 8192) = (f32x4){0.f, 0.f, 0.f, 0.f};
  // x(t=0) -> XT[0]
  const int xb = tid >> 5, xk4 = (tid & 31) * 4;
  {
    f32x4 v = *(const f32x4*)(x + ((size_t)(blockIdx.x * 16 + xb) * T_INS) * 128 + xk4);
    half4v hx;
    hx[0] = (_Float16)v[0]; hx[1] = (_Float16)v[1];
    hx[2] = (_Float16)v[2]; hx[3] = (_Float16)v[3];
    *(half4v*)(sm + XTO + OFF(xb, xk4)) = hx;
  }

  // biases register-resident, pre-scaled; injected as first-MFMA C operand.
  f32x4 bias0[4], bias1[4];
#pragma unroll
  for (int mt = 0; mt < 4; ++mt) {
    int u = u0 + mt;
#pragma unroll
    for (int q = 0; q < 4; ++q) {
      float s = PACKED ? ((q == 2) ? 2.88539008f : -1.44269504f) : 1.0f;
      bias0[mt][q] = s * (b_ih[q * 128 + u] + b_hh[q * 128 + u]);
      bias1[mt][q] = s * (b_ih[512 + q * 128 + u] + b_hh[512 + q * 128 + u]);
    }
  }

  // ALL FOUR weight matrices register-resident: 64 half8 = 256 regs/wave.
  half8 wi0r[4][4], whh0[4][4], whh1[4][4], wi1[4][4];
  if (PACKED) {
    const char* base = ws + (size_t)lane * 16;
#pragma unroll
    for (int mt = 0; mt < 4; ++mt)
#pragma unroll
      for (int kf = 0; kf < 4; ++kf) {
        int fo = (w * 16 + mt * 4 + kf) * 1024;
        wi1[mt][kf]  = *(const half8*)(base + fo);
        whh0[mt][kf] = *(const half8*)(base + 131072 + fo);
        whh1[mt][kf] = *(const half8*)(base + 262144 + fo);
        wi0r[mt][kf] = *(const half8*)(base + 393216 + fo);
      }
  } else {
#pragma unroll
    for (int mt = 0; mt < 4; ++mt)
#pragma unroll
      for (int kf = 0; kf < 4; ++kf) {
        int row = perm_row8(w, mt, lb);
        wi0r[mt][kf] = cvt_frag(W_ih + (size_t)row * 128 + kf * 32 + k0b);
        wi1[mt][kf]  = cvt_frag(W_ih + (size_t)(512 + row) * 128 + kf * 32 + k0b);
        whh0[mt][kf] = cvt_frag(W_hh + (size_t)row * 128 + kf * 32 + k0b);
        whh1[mt][kf] = cvt_frag(W_hh + (size_t)(512 + row) * 128 + kf * 32 + k0b);
      }
  }

  float c0[4], c1[4];
  half4v hp0v, hp1v;
#pragma unroll
  for (int i = 0; i < 4; ++i) {
    c0[i] = c1[i] = 0.f;
    hp0v[i] = (_Float16)0.f; hp1v[i] = (_Float16)0.f;
  }
  __syncthreads();

  // strength-reduced pointers
  const float* xptr = x + ((size_t)(blockIdx.x * 16 + xb) * T_INS + 1) * 128 + xk4;
  float* optr = out + (size_t)batch * 25600 + u0;
  const size_t obase_ar = 13107200ull + (size_t)batch * 25600 + u0;

  for (int t = 0; t < 400; ++t) {
    const int p = t & 1;
    const bool doX = (t < 199);
    f32x4 xpre = (f32x4){0.f, 0.f, 0.f, 0.f};
    if (doX) { xpre = *(const f32x4*)xptr; xptr += 128; }
    const bool mk = (t < 200) ? (t < Lin) : ((t - 200) < Lar);

    // ================= layer 0 =================
    f32x4 acc[4];
    {
      const char* sX = (t < 200) ? (sm + XTO + p * 4096) : (sm + H1O + p * 4096);
      const char* sH = sm + H0O + (p ^ 1) * 4096;
      half8 bf[4];
      // hh (resident) first; bias enters as C of the first MFMA per chain
      READ_BF(bf, sH);
#pragma unroll
      for (int mt = 0; mt < 4; ++mt)
        acc[mt] = __builtin_amdgcn_mfma_f32_16x16x32_f16(whh0[mt][0], bf[0],
                                                         bias0[mt], 0, 0, 0);
#pragma unroll
      for (int kf = 1; kf < 4; ++kf)
#pragma unroll
        for (int mt = 0; mt < 4; ++mt)
          acc[mt] = __builtin_amdgcn_mfma_f32_16x16x32_f16(whh0[mt][kf], bf[kf],
                                                           acc[mt], 0, 0, 0);
      READ_BF(bf, sX);
#pragma unroll
      for (int kf = 0; kf < 4; ++kf)
#pragma unroll
        for (int mt = 0; mt < 4; ++mt)
          acc[mt] = __builtin_amdgcn_mfma_f32_16x16x32_f16(wi0r[mt][kf], bf[kf],
                                                           acc[mt], 0, 0, 0);
    }
    // ACT0
    {
      _Float16 h4[4];
#pragma unroll
      for (int mt = 0; mt < 4; ++mt)
        h4[mt] = (_Float16)gates<PACKED>(acc[mt], c0[mt], mk);
      hp0v = mk ? *(half4v*)h4 : hp0v;
      *(half4v*)(sm + H0O + p * 4096 + OFF(lb, u0)) = hp0v;
    }
    BARRIER();  // h0[p] published; vmem stays in flight

    // stage x(t+1) into XT[p^1]
    if (doX) {
      half4v hx;
      hx[0] = (_Float16)xpre[0]; hx[1] = (_Float16)xpre[1];
      hx[2] = (_Float16)xpre[2]; hx[3] = (_Float16)xpre[3];
      *(half4v*)(sm + XTO + (p ^ 1) * 4096 + OFF(xb, xk4)) = hx;
    }

    // ================= layer 1 =================
    {
      const char* sX = sm + H0O + p * 4096;  // fresh h0(t)
      const char* sH = sm + H1O + p * 4096;  // h1(t-1)
      half8 bf[4];
      READ_BF(bf, sH);
#pragma unroll
      for (int mt = 0; mt < 4; ++mt)
        acc[mt] = __builtin_amdgcn_mfma_f32_16x16x32_f16(whh1[mt][0], bf[0],
                                                         bias1[mt], 0, 0, 0);
#pragma unroll
      for (int kf = 1; kf < 4; ++kf)
#pragma unroll
        for (int mt = 0; mt < 4; ++mt)
          acc[mt] = __builtin_amdgcn_mfma_f32_16x16x32_f16(whh1[mt][kf], bf[kf],
                                                           acc[mt], 0, 0, 0);
      READ_BF(bf, sX);
#pragma unroll
      for (int kf = 0; kf < 4; ++kf)
#pragma unroll
        for (int mt = 0; mt < 4; ++mt)
          acc[mt] = __builtin_amdgcn_mfma_f32_16x16x32_f16(wi1[mt][kf], bf[kf],
                                                           acc[mt], 0, 0, 0);
    }
    // ACT1 + output
    {
      _Float16 h4[4];
      f32x4 vo;
#pragma unroll
      for (int mt = 0; mt < 4; ++mt) {
        float hn = gates<PACKED>(acc[mt], c1[mt], mk);
        h4[mt] = (_Float16)hn;
        vo[mt] = mk ? hn : 0.0f;
      }
      hp1v = mk ? *(half4v*)h4 : hp1v;
      *(half4v*)(sm + H1O + (p ^ 1) * 4096 + OFF(lb, u0)) = hp1v;
      *(f32x4*)optr = vo;
      optr += 128;
      if (t == 199) optr = out + obase_ar;
    }
    BARRIER();  // h1[p^1], XT[p^1] published
  }
}

extern "C" void kernel_launch(void* const* d_in, const int* in_sizes, int n_in,
                              void* d_out, int out_size, void* d_ws, size_t ws_size,
                              hipStream_t stream) {
  (void)in_sizes; (void)n_in; (void)out_size;
  const float* x = (const float*)d_in[0];
  const int* len_in = (const int*)d_in[1];
  const int* len_ar = (const int*)d_in[2];
  // d_in[3] = mask_aureg unused (monotone mask recomputed from lengths)
  const float* W_ih = (const float*)d_in[4];
  const float* W_hh = (const float*)d_in[5];
  const float* b_ih = (const float*)d_in[6];
  const float* b_hh = (const float*)d_in[7];
  float* out = (float*)d_out;
  char* ws = (char*)d_ws;

  if (ws_size >= WSZ_PACK) {
    pack_kernel<<<dim3(128), dim3(256), 0, stream>>>(W_ih, W_hh, ws);
    lstm_kernel<1><<<dim3(32), dim3(512), 0, stream>>>(x, len_in, len_ar, W_ih,
                                                       W_hh, b_ih, b_hh, ws, out);
  } else {
    lstm_kernel<0><<<dim3(32), dim3(512), 0, stream>>>(x, len_in, len_ar, W_ih,
                                                       W_hh, b_ih, b_hh, ws, out);
  }
}

// Round 13
// 1603.914 us; speedup vs baseline: 1.6419x; 1.6419x over previous
//
#include <hip/hip_runtime.h>
#include <hip/hip_fp16.h>

typedef _Float16 half8 __attribute__((ext_vector_type(8)));
typedef _Float16 half4v __attribute__((ext_vector_type(4)));
typedef float f32x4 __attribute__((ext_vector_type(4)));

#define T_INS 200

// LDS layout (bytes): W_ih[0] frags + h/x tiles (bias now register-resident)
constexpr int WI0O = 0;       // 128 KiB: W_ih[0] as MFMA A-fragments
constexpr int H0O  = 131072;  // 2 x 4096 (parity)
constexpr int H1O  = 139264;  // 2 x 4096
constexpr int XTO  = 147456;  // 2 x 4096
constexpr int SMSZ = 155648;  // 152 KiB

constexpr size_t WSZ_PACK = 524288;  // 4 x 128KB frag regions

// swizzled [batch][k(half)] f16 layout (2-way max bank aliasing on b128)
#define OFF(b, k) (((((b) << 8) | ((k) << 1))) ^ (((b) & 7) << 4))

// counted barrier: wait until <=n lgkm ops outstanding (DS completes in-order,
// so the h-write issued before the n trailing prefetch reads is visible),
// then barrier. Validated pattern (R9/R10 passed).
#define BAR_K(n) asm volatile("s_waitcnt lgkmcnt(" #n ")\n\ts_barrier" ::: "memory")

__device__ __forceinline__ float sigm(float x) {
  return __builtin_amdgcn_rcpf(1.0f + __builtin_amdgcn_exp2f(-1.44269504f * x));
}
__device__ __forceinline__ float tanh_f(float x) {
  return 1.0f - 2.0f * __builtin_amdgcn_rcpf(1.0f + __builtin_amdgcn_exp2f(2.88539008f * x));
}
__device__ __forceinline__ half8 cvt_frag(const float* __restrict__ src) {
  f32x4 a = *(const f32x4*)src;
  f32x4 b = *(const f32x4*)(src + 4);
  half8 h;
  h[0] = (_Float16)a[0]; h[1] = (_Float16)a[1]; h[2] = (_Float16)a[2]; h[3] = (_Float16)a[3];
  h[4] = (_Float16)b[0]; h[5] = (_Float16)b[1]; h[6] = (_Float16)b[2]; h[7] = (_Float16)b[3];
  return h;
}
__device__ __forceinline__ half8 cvt_frag_s(const float* __restrict__ src, float s) {
  f32x4 a = *(const f32x4*)src;
  f32x4 b = *(const f32x4*)(src + 4);
  half8 h;
  h[0] = (_Float16)(s * a[0]); h[1] = (_Float16)(s * a[1]);
  h[2] = (_Float16)(s * a[2]); h[3] = (_Float16)(s * a[3]);
  h[4] = (_Float16)(s * b[0]); h[5] = (_Float16)(s * b[1]);
  h[6] = (_Float16)(s * b[2]); h[7] = (_Float16)(s * b[3]);
  return h;
}
// 8-wave row permutation: gate = r&3, unit = w*16 + (r>>2)*4 + mt
__device__ __forceinline__ int perm_row8(int w, int mt, int r) {
  return (r & 3) * 128 + w * 16 + (r >> 2) * 4 + mt;
}

// gates with pre-scaled z (SCALED: i,f,o rows x -log2e; g rows x 2*log2e)
template <int SCALED>
__device__ __forceinline__ float gates(const f32x4 a, float& c, bool mk) {
  float si, sf, tg, so;
  if (SCALED) {
    si = __builtin_amdgcn_rcpf(1.0f + __builtin_amdgcn_exp2f(a[0]));
    sf = __builtin_amdgcn_rcpf(1.0f + __builtin_amdgcn_exp2f(a[1]));
    tg = 1.0f - 2.0f * __builtin_amdgcn_rcpf(1.0f + __builtin_amdgcn_exp2f(a[2]));
    so = __builtin_amdgcn_rcpf(1.0f + __builtin_amdgcn_exp2f(a[3]));
  } else {
    si = sigm(a[0]); sf = sigm(a[1]); tg = tanh_f(a[2]); so = sigm(a[3]);
  }
  float cn = sf * c + si * tg;
  float hn = so * tanh_f(cn);
  c = mk ? cn : c;
  return hn;
}

// Pack into ws (PRE-SCALED rows): region 0 = W_ih[1], 1 = W_hh[0],
// 2 = W_hh[1], 3 = W_ih[0]. Frag F = w*16 + mt*4 + kf; 64 lanes x 16B.
__global__ __launch_bounds__(256) void pack_kernel(const float* __restrict__ W_ih,
                                                   const float* __restrict__ W_hh,
                                                   char* __restrict__ ws) {
  int gid = blockIdx.x * 256 + threadIdx.x;  // 32768 threads exactly
  int G = gid >> 6, lane = gid & 63;
  int region = G >> 7, F = G & 127;
  int w = F >> 4, mt = (F >> 2) & 3, kf = F & 3;
  int r = lane & 15;
  int row = perm_row8(w, mt, r);
  int k0 = kf * 32 + (lane >> 4) * 8;
  float s = ((r & 3) == 2) ? 2.88539008f : -1.44269504f;
  const float* src;
  if (region == 0)      src = W_ih + (size_t)(512 + row) * 128 + k0;
  else if (region == 3) src = W_ih + (size_t)row * 128 + k0;
  else                  src = W_hh + (size_t)((region - 1) * 512 + row) * 128 + k0;
  *(half8*)(ws + (size_t)G * 1024 + lane * 16) = cvt_frag_s(src, s);
}

#define READ_BF(BF, BASE)                                                     \
  _Pragma("unroll") for (int kf = 0; kf < 4; ++kf)                            \
      BF[kf] = *(const half8*)((BASE) + OFF(lb, kf * 32 + k0b));

// H-side MFMA block: bias enters as C of the first MFMA of each chain
#define MFMA_H(ACC, WREG, BF, BIAS)                                           \
  _Pragma("unroll") for (int mt = 0; mt < 4; ++mt)                            \
      ACC[mt] = __builtin_amdgcn_mfma_f32_16x16x32_f16(WREG[mt][0], BF[0],    \
                                                       BIAS[mt], 0, 0, 0);    \
  _Pragma("unroll") for (int kf = 1; kf < 4; ++kf)                            \
      _Pragma("unroll") for (int mt = 0; mt < 4; ++mt)                        \
          ACC[mt] = __builtin_amdgcn_mfma_f32_16x16x32_f16(WREG[mt][kf],      \
                                                           BF[kf], ACC[mt], 0, 0, 0);

#define MFMA_X(ACC, WREG, BF)                                                 \
  _Pragma("unroll") for (int kf = 0; kf < 4; ++kf)                            \
      _Pragma("unroll") for (int mt = 0; mt < 4; ++mt)                        \
          ACC[mt] = __builtin_amdgcn_mfma_f32_16x16x32_f16(WREG[mt][kf],      \
                                                           BF[kf], ACC[mt], 0, 0, 0);

#define MFMA_WI0(ACC, BF)                                                     \
  _Pragma("unroll") for (int kf = 0; kf < 4; ++kf)                            \
      _Pragma("unroll") for (int mt = 0; mt < 4; ++mt) {                      \
        half8 a_ = *(const half8*)(wi0base + (mt * 4 + kf) * 1024);           \
        ACC[mt] = __builtin_amdgcn_mfma_f32_16x16x32_f16(a_, BF[kf], ACC[mt], 0, 0, 0); \
      }

template <int PACKED>
__global__ __launch_bounds__(512, 2) void lstm_kernel(
    const float* __restrict__ x, const int* __restrict__ len_in,
    const int* __restrict__ len_ar, const float* __restrict__ W_ih,
    const float* __restrict__ W_hh, const float* __restrict__ b_ih,
    const float* __restrict__ b_hh, const char* __restrict__ ws,
    float* __restrict__ out) {
  __shared__ __attribute__((aligned(16))) char sm[SMSZ];

  const int tid = threadIdx.x;
  const int w = tid >> 6, lane = tid & 63;
  const int lb = lane & 15, lg = lane >> 4;
  const int k0b = lg * 8;
  const int u0 = w * 16 + lg * 4;  // lane's 4 contiguous units: u0..u0+3
  const int batch = blockIdx.x * 16 + lb;
  const int Lin = len_in[batch];
  const int Lar = len_ar[batch];

  // ---- one-time init ----
  if (PACKED) {
    for (int j = 0; j < 16; ++j) {
      int pos = j * 8192 + tid * 16;
      *(half8*)(sm + WI0O + pos) = *(const half8*)(ws + 393216 + pos);
    }
  } else {
    for (int j = 0; j < 16; ++j) {
      int pos = tid * 256 + j * 16;
      int F = pos >> 10, ln = (pos >> 4) & 63;
      int fw = F >> 4, fmt = (F >> 2) & 3, fkf = F & 3;
      int row = perm_row8(fw, fmt, ln & 15);
      int k0 = fkf * 32 + (ln >> 4) * 8;
      *(half8*)(sm + WI0O + pos) = cvt_frag(W_ih + (size_t)row * 128 + k0);
    }
  }
  // zero h0/h1 (both parities)
#pragma unroll
  for (int i = 0; i < 2; ++i)
    *(f32x4*)(sm + H0O + tid * 16 + i * 8192) = (f32x4){0.f, 0.f, 0.f, 0.f};
  // x(t=0) -> XT[0]
  const int xb = tid >> 5, xk4 = (tid & 31) * 4;
  {
    f32x4 v = *(const f32x4*)(x + ((size_t)(blockIdx.x * 16 + xb) * T_INS) * 128 + xk4);
    half4v hx;
    hx[0] = (_Float16)v[0]; hx[1] = (_Float16)v[1];
    hx[2] = (_Float16)v[2]; hx[3] = (_Float16)v[3];
    *(half4v*)(sm + XTO + OFF(xb, xk4)) = hx;
  }

  // biases register-resident (pre-scaled), injected as first-MFMA C operand
  f32x4 bias0[4], bias1[4];
#pragma unroll
  for (int mt = 0; mt < 4; ++mt) {
    int u = u0 + mt;
#pragma unroll
    for (int q = 0; q < 4; ++q) {
      float s = PACKED ? ((q == 2) ? 2.88539008f : -1.44269504f) : 1.0f;
      bias0[mt][q] = s * (b_ih[q * 128 + u] + b_hh[q * 128 + u]);
      bias1[mt][q] = s * (b_ih[512 + q * 128 + u] + b_hh[512 + q * 128 + u]);
    }
  }

  // resident weights: 48 half8 = 192 regs/wave (proven budget ceiling)
  half8 whh0[4][4], whh1[4][4], wi1[4][4];
  if (PACKED) {
    const char* base = ws + (size_t)lane * 16;
#pragma unroll
    for (int mt = 0; mt < 4; ++mt)
#pragma unroll
      for (int kf = 0; kf < 4; ++kf) {
        int fo = (w * 16 + mt * 4 + kf) * 1024;
        wi1[mt][kf]  = *(const half8*)(base + fo);
        whh0[mt][kf] = *(const half8*)(base + 131072 + fo);
        whh1[mt][kf] = *(const half8*)(base + 262144 + fo);
      }
  } else {
#pragma unroll
    for (int mt = 0; mt < 4; ++mt)
#pragma unroll
      for (int kf = 0; kf < 4; ++kf) {
        int row = perm_row8(w, mt, lb);
        wi1[mt][kf]  = cvt_frag(W_ih + (size_t)(512 + row) * 128 + kf * 32 + k0b);
        whh0[mt][kf] = cvt_frag(W_hh + (size_t)row * 128 + kf * 32 + k0b);
        whh1[mt][kf] = cvt_frag(W_hh + (size_t)(512 + row) * 128 + kf * 32 + k0b);
      }
  }

  float c0[4], c1[4];
  half4v hp0v, hp1v;
#pragma unroll
  for (int i = 0; i < 4; ++i) {
    c0[i] = c1[i] = 0.f;
    hp0v[i] = (_Float16)0.f; hp1v[i] = (_Float16)0.f;
  }
  __syncthreads();

  const char* wi0base = sm + WI0O + w * 16384 + lane * 16;
  const float* xptr = x + ((size_t)(blockIdx.x * 16 + xb) * T_INS + 1) * 128 + xk4;
  float* optr = out + (size_t)batch * 25600 + u0;
  const size_t obase_ar = 13107200ull + (size_t)batch * 25600 + u0;

  f32x4 acc[4];
  half8 bfA[4], bfB[4];
  // carry-in: bfA = h0(-1) = 0 @ H0O parity 1
  READ_BF(bfA, sm + H0O + 4096);

  // ================= TF loop: 2 barriers/step, carries + trailing prefetch ====
  for (int t = 0; t < 200; ++t) {
    const int p = t & 1;
    const bool doX = (t < 199);
    f32x4 xpre = (f32x4){0.f, 0.f, 0.f, 0.f};
    if (doX) { xpre = *(const f32x4*)xptr; xptr += 128; }
    const bool mk = t < Lin;

    // ---- layer 0: H-side on carried bfA (zero-wait), X = x(t) from LDS ----
    MFMA_H(acc, whh0, bfA, bias0);
    READ_BF(bfB, sm + XTO + p * 4096);
    MFMA_WI0(acc, bfB);
    // ACT0
    {
      _Float16 h4[4];
#pragma unroll
      for (int mt = 0; mt < 4; ++mt)
        h4[mt] = (_Float16)gates<PACKED>(acc[mt], c0[mt], mk);
      hp0v = mk ? *(half4v*)h4 : hp0v;
      *(half4v*)(sm + H0O + p * 4096 + OFF(lb, u0)) = hp0v;
    }
    // prefetch L1's H-operand h1(t-1) @ H1O[p] (stable since step t-1) --
    // these 4 reads trail across the barrier; h0-write (issued first,
    // in-order completion) is visible once <=4 remain.
    READ_BF(bfB, sm + H1O + p * 4096);
    BAR_K(4);  // h0[p] published

    // stage x(t+1) into XT[p^1]
    if (doX) {
      half4v hx;
      hx[0] = (_Float16)xpre[0]; hx[1] = (_Float16)xpre[1];
      hx[2] = (_Float16)xpre[2]; hx[3] = (_Float16)xpre[3];
      *(half4v*)(sm + XTO + (p ^ 1) * 4096 + OFF(xb, xk4)) = hx;
    }

    // ---- layer 1: H-side on prefetched bfB, X = fresh h0(t) (carried out) --
    MFMA_H(acc, whh1, bfB, bias1);
    READ_BF(bfA, sm + H0O + p * 4096);  // h0(t): used here AND next step's L0-H
    MFMA_X(acc, wi1, bfA);
    // ACT1 + output
    {
      _Float16 h4[4];
      f32x4 vo;
#pragma unroll
      for (int mt = 0; mt < 4; ++mt) {
        float hn = gates<PACKED>(acc[mt], c1[mt], mk);
        h4[mt] = (_Float16)hn;
        vo[mt] = mk ? hn : 0.0f;
      }
      hp1v = mk ? *(half4v*)h4 : hp1v;
      *(half4v*)(sm + H1O + (p ^ 1) * 4096 + OFF(lb, u0)) = hp1v;
      *(f32x4*)optr = vo;
      optr += 128;
    }
    BAR_K(0);  // h1[p^1], XT[p^1] published
  }
  optr = out + obase_ar;

  // ================= AR loop: X-operands double as next H-operands ==========
  for (int t = 200; t < 400; ++t) {
    const int p = t & 1;
    const bool mk = (t - 200) < Lar;

    // ---- layer 0: H = carried h0(t-1); X = h1(t-1) (kept for L1's H) ----
    MFMA_H(acc, whh0, bfA, bias0);
    READ_BF(bfB, sm + H1O + p * 4096);
    MFMA_WI0(acc, bfB);
    {
      _Float16 h4[4];
#pragma unroll
      for (int mt = 0; mt < 4; ++mt)
        h4[mt] = (_Float16)gates<PACKED>(acc[mt], c0[mt], mk);
      hp0v = mk ? *(half4v*)h4 : hp0v;
      *(half4v*)(sm + H0O + p * 4096 + OFF(lb, u0)) = hp0v;
    }
    BAR_K(0);  // h0[p] published

    // ---- layer 1: H = carried bfB (h1(t-1)); X = fresh h0(t) (carried out) --
    MFMA_H(acc, whh1, bfB, bias1);
    READ_BF(bfA, sm + H0O + p * 4096);
    MFMA_X(acc, wi1, bfA);
    {
      _Float16 h4[4];
      f32x4 vo;
#pragma unroll
      for (int mt = 0; mt < 4; ++mt) {
        float hn = gates<PACKED>(acc[mt], c1[mt], mk);
        h4[mt] = (_Float16)hn;
        vo[mt] = mk ? hn : 0.0f;
      }
      hp1v = mk ? *(half4v*)h4 : hp1v;
      *(half4v*)(sm + H1O + (p ^ 1) * 4096 + OFF(lb, u0)) = hp1v;
      *(f32x4*)optr = vo;
      optr += 128;
    }
    BAR_K(0);  // h1[p^1] published
  }
}

extern "C" void kernel_launch(void* const* d_in, const int* in_sizes, int n_in,
                              void* d_out, int out_size, void* d_ws, size_t ws_size,
                              hipStream_t stream) {
  (void)in_sizes; (void)n_in; (void)out_size;
  const float* x = (const float*)d_in[0];
  const int* len_in = (const int*)d_in[1];
  const int* len_ar = (const int*)d_in[2];
  // d_in[3] = mask_aureg unused (monotone mask recomputed from lengths)
  const float* W_ih = (const float*)d_in[4];
  const float* W_hh = (const float*)d_in[5];
  const float* b_ih = (const float*)d_in[6];
  const float* b_hh = (const float*)d_in[7];
  float* out = (float*)d_out;
  char* ws = (char*)d_ws;

  if (ws_size >= WSZ_PACK) {
    pack_kernel<<<dim3(128), dim3(256), 0, stream>>>(W_ih, W_hh, ws);
    lstm_kernel<1><<<dim3(32), dim3(512), 0, stream>>>(x, len_in, len_ar, W_ih,
                                                       W_hh, b_ih, b_hh, ws, out);
  } else {
    lstm_kernel<0><<<dim3(32), dim3(512), 0, stream>>>(x, len_in, len_ar, W_ih,
                                                       W_hh, b_ih, b_hh, ws, out);
  }
}